// Round 4
// baseline (878.621 us; speedup 1.0000x reference)
//
#include <hip/hip_runtime.h>
#include <math.h>

#define DD 64
#define HIDN 32
#define NH 3
#define KMAX 4                      // fast-path: up to 4*64 = 256 atoms/segment in regs
#define SMAX_FAST (KMAX * 64)
#define SMAX_LDS 512                // fused-fallback LDS capacity
#define SROWS 256                   // atoms staged per scores_k block
#define SPITCH 65                   // LDS row pitch in floats: bank=(t+d)%32 -> 2-way (free)

// ---------------------------------------------------------------------------
// Kernel 1: segment offsets. seg_start[g] = first index i with owner[i] >= g
// (lower_bound). owner is sorted. Handles empty segments via gap fill.
// ---------------------------------------------------------------------------
__global__ void seg_offsets_k(const int* __restrict__ owner, int N, int G,
                              int* __restrict__ seg_start) {
    int i = blockIdx.x * blockDim.x + threadIdx.x;
    if (i >= N) return;
    int cur  = owner[i];
    int prev = (i == 0) ? -1 : owner[i - 1];
    for (int g = prev + 1; g <= cur; ++g) seg_start[g] = i;
    if (i == N - 1) {
        for (int g = cur + 1; g <= G; ++g) seg_start[g] = N;
    }
}

// ---------------------------------------------------------------------------
// Per-atom MLP (generic version, used by fallback paths).
// ---------------------------------------------------------------------------
static __device__ __forceinline__ void mlp_scores(
    const float* __restrict__ fr, const float* __restrict__ w1,
    const float* __restrict__ b1, const float* __restrict__ w2,
    const float* __restrict__ b2, float& s0, float& s1, float& s2) {
    float hid[HIDN];
#pragma unroll
    for (int j = 0; j < HIDN; ++j) hid[j] = b1[j];

    const float4* fr4 = (const float4*)fr;
    for (int q = 0; q < DD / 4; ++q) {
        float4 f = fr4[q];
        const float* w1r = w1 + (q * 4) * HIDN;
#pragma unroll
        for (int j = 0; j < HIDN; ++j) {
            hid[j] += f.x * w1r[j];
            hid[j] += f.y * w1r[HIDN + j];
            hid[j] += f.z * w1r[2 * HIDN + j];
            hid[j] += f.w * w1r[3 * HIDN + j];
        }
    }
    s0 = b2[0]; s1 = b2[1]; s2 = b2[2];
#pragma unroll
    for (int j = 0; j < HIDN; ++j) {
        float v = hid[j];
        v = v * __builtin_amdgcn_rcpf(1.0f + __expf(-v));   // silu
        s0 += v * w2[j * NH + 0];
        s1 += v * w2[j * NH + 1];
        s2 += v * w2[j * NH + 2];
    }
}

static __device__ __forceinline__ float wave_max(float v) {
#pragma unroll
    for (int m = 32; m >= 1; m >>= 1) v = fmaxf(v, __shfl_xor(v, m, 64));
    return v;
}
static __device__ __forceinline__ float wave_sum(float v) {
#pragma unroll
    for (int m = 32; m >= 1; m >>= 1) v += __shfl_xor(v, m, 64);
    return v;
}

// ---------------------------------------------------------------------------
// Kernel 2 (split path): atom-parallel score MLP with LDS row staging.
// Block cooperatively loads its 256 atom rows (64KB) with grid-linear float4
// loads: each 128B line is fully consumed WITHIN one instruction by 8
// consecutive lanes -> over-fetch structurally impossible (no cache-residency
// dependence, unlike the L1-thrashed direct version: 1.6GB fetch for 0.5GB).
// Then thread t runs the MLP for atom t from LDS (pitch 65 -> 2-way banks).
// Math order identical to mlp_scores (q ascending, j ascending).
// ---------------------------------------------------------------------------
__global__ void __launch_bounds__(256) scores_k(
    const float* __restrict__ feas, const float* __restrict__ w1,
    const float* __restrict__ b1, const float* __restrict__ w2,
    const float* __restrict__ b2, int N, float4* __restrict__ scores) {
    __shared__ float xs[SROWS * SPITCH];        // 66560 B -> 2 blocks/CU
    const int t = threadIdx.x;
    const int blockBase = blockIdx.x * SROWS;
    const int nAtoms = min(SROWS, N - blockBase);

    // ---- stage: nAtoms*16 float4s, block-linear (perfectly coalesced)
    const float4* src = (const float4*)(feas + (size_t)blockBase * DD);
    for (int idx = t; idx < nAtoms * 16; idx += 256) {
        const int row = idx >> 4;        // atom within block
        const int q   = idx & 15;        // float4 within row
        float4 v = src[idx];
        float* dst = &xs[row * SPITCH + q * 4];
        dst[0] = v.x; dst[1] = v.y; dst[2] = v.z; dst[3] = v.w;
    }
    __syncthreads();
    if (t >= nAtoms) return;

    // ---- MLP from LDS (scalar reads, (t+d)%32 banks -> 2-way, free)
    const float* fr = &xs[t * SPITCH];
    float hid[HIDN];
#pragma unroll
    for (int j = 0; j < HIDN; ++j) hid[j] = b1[j];

    for (int q = 0; q < DD / 4; ++q) {
        const float fx = fr[4 * q + 0];
        const float fy = fr[4 * q + 1];
        const float fz = fr[4 * q + 2];
        const float fw = fr[4 * q + 3];
        const float* w1r = w1 + (q * 4) * HIDN;
#pragma unroll
        for (int j = 0; j < HIDN; ++j) {
            hid[j] += fx * w1r[j];
            hid[j] += fy * w1r[HIDN + j];
            hid[j] += fz * w1r[2 * HIDN + j];
            hid[j] += fw * w1r[3 * HIDN + j];
        }
    }
    float s0 = b2[0], s1 = b2[1], s2 = b2[2];
#pragma unroll
    for (int j = 0; j < HIDN; ++j) {
        float v = hid[j];
        v = v * __builtin_amdgcn_rcpf(1.0f + __expf(-v));   // silu
        s0 += v * w2[j * NH + 0];
        s1 += v * w2[j * NH + 1];
        s2 += v * w2[j * NH + 2];
    }
    scores[blockBase + t] = make_float4(s0, s1, s2, 0.0f);
}

// ---------------------------------------------------------------------------
// Big-segment pooling fallback (seg > 256). Rare/never (mean seg = 40).
// ---------------------------------------------------------------------------
static __device__ __attribute__((noinline)) void big_pool(
    const float* __restrict__ feas, const float4* __restrict__ scores,
    int lo, int hi, int lane, float* __restrict__ outg) {
    float m0 = -INFINITY, m1 = -INFINITY, m2 = -INFINITY;
    for (int i = lo + lane; i < hi; i += 64) {
        float4 s = scores[i];
        m0 = fmaxf(m0, s.x); m1 = fmaxf(m1, s.y); m2 = fmaxf(m2, s.z);
    }
    m0 = wave_max(m0); m1 = wave_max(m1); m2 = wave_max(m2);
    float d0 = 0.f, d1 = 0.f, d2 = 0.f;
    for (int i = lo + lane; i < hi; i += 64) {
        float4 s = scores[i];
        d0 += __expf(s.x - m0); d1 += __expf(s.y - m1); d2 += __expf(s.z - m2);
    }
    d0 = wave_sum(d0); d1 = wave_sum(d1); d2 = wave_sum(d2);
    float a0 = 0.f, a1 = 0.f, a2 = 0.f;
    for (int base = lo; base < hi; base += 64) {
        int i = base + lane;
        float e0v = 0.f, e1v = 0.f, e2v = 0.f;
        if (i < hi) {
            float4 s = scores[i];
            e0v = __expf(s.x - m0); e1v = __expf(s.y - m1); e2v = __expf(s.z - m2);
        }
        int cnt = min(64, hi - base);
        for (int j = 0; j < cnt; ++j) {
            float f = feas[(size_t)(base + j) * DD + lane];
            a0 += f * __shfl(e0v, j, 64);
            a1 += f * __shfl(e1v, j, 64);
            a2 += f * __shfl(e2v, j, 64);
        }
    }
    outg[lane * 3 + 0] = a0 * __builtin_amdgcn_rcpf(d0);
    outg[lane * 3 + 1] = a1 * __builtin_amdgcn_rcpf(d1);
    outg[lane * 3 + 2] = a2 * __builtin_amdgcn_rcpf(d2);
}

static __device__ __forceinline__ float4 xor_reduce_16_32(float4 v) {
#pragma unroll
    for (int m = 16; m <= 32; m <<= 1) {
        v.x += __shfl_xor(v.x, m, 64);
        v.y += __shfl_xor(v.y, m, 64);
        v.z += __shfl_xor(v.z, m, 64);
        v.w += __shfl_xor(v.w, m, 64);
    }
    return v;
}

// ---------------------------------------------------------------------------
// Kernel 3 (split path): segment softmax + weighted pooling.
// 4 waves/block, one segment per wave, ZERO LDS, no barriers.
// Phase 3: 4 atoms x float4-dims per instruction -> 1KB coalesced loads.
// ---------------------------------------------------------------------------
__global__ void __launch_bounds__(256) pool_k(
    const float* __restrict__ feas, const float4* __restrict__ scores,
    const int* __restrict__ seg_start, int G, float* __restrict__ out) {
    const int gi = blockIdx.x * 4 + (threadIdx.x >> 6);
    const int lane = threadIdx.x & 63;
    if (gi >= G) return;
    const int g = G - 1 - gi;                 // reverse order: L3 reuse
    const int lo = seg_start[g];
    const int hi = seg_start[g + 1];
    const int seg = hi - lo;
    float* outg = out + (size_t)g * (DD * NH);

    if (seg <= 0) {   // empty segment: reference segment_sum gives zeros
        outg[lane] = 0.f; outg[lane + 64] = 0.f; outg[lane + 128] = 0.f;
        return;
    }
    if (seg > SMAX_FAST) {
        big_pool(feas, scores, lo, hi, lane, outg);
        return;
    }

    // ---- Phase 1: scores -> registers (lane = atom within chunk)
    float e0[KMAX], e1[KMAX], e2[KMAX];
    float m0 = -INFINITY, m1 = -INFINITY, m2 = -INFINITY;
#pragma unroll
    for (int k = 0; k < KMAX; ++k) {
        int i = k * 64 + lane;
        if (i < seg) {
            float4 s = scores[lo + i];
            e0[k] = s.x; e1[k] = s.y; e2[k] = s.z;
        } else {
            e0[k] = -INFINITY; e1[k] = -INFINITY; e2[k] = -INFINITY;
        }
        m0 = fmaxf(m0, e0[k]); m1 = fmaxf(m1, e1[k]); m2 = fmaxf(m2, e2[k]);
    }
    m0 = wave_max(m0); m1 = wave_max(m1); m2 = wave_max(m2);

    // ---- Phase 2: exp + denominators (exp(-inf - m) = 0 pads naturally)
    float d0 = 0.f, d1 = 0.f, d2 = 0.f;
#pragma unroll
    for (int k = 0; k < KMAX; ++k) {
        if (k * 64 < seg) {
            e0[k] = __expf(e0[k] - m0); d0 += e0[k];
            e1[k] = __expf(e1[k] - m1); d1 += e1[k];
            e2[k] = __expf(e2[k] - m2); d2 += e2[k];
        } else {
            e0[k] = 0.f; e1[k] = 0.f; e2[k] = 0.f;
        }
    }
    d0 = wave_sum(d0); d1 = wave_sum(d1); d2 = wave_sum(d2);
    const float rd0 = __builtin_amdgcn_rcpf(d0);
    const float rd1 = __builtin_amdgcn_rcpf(d1);
    const float rd2 = __builtin_amdgcn_rcpf(d2);

    // ---- Phase 3: 4 atoms x float4-dims per instruction, fully coalesced
    const int sub = lane >> 4;        // atom residue 0..3
    const int c   = lane & 15;        // dim quad: dims 4c..4c+3
    float4 A0 = make_float4(0.f, 0.f, 0.f, 0.f);
    float4 A1 = A0, A2 = A0;
#pragma unroll
    for (int k = 0; k < KMAX; ++k) {
        if (k * 64 < seg) {
            const int cnt = min(64, seg - k * 64);
            const float* base = feas + (size_t)(lo + k * 64) * DD;
            for (int j = 0; j < cnt; j += 4) {
                const int a = j + sub;                  // atom within chunk
                float w0 = __shfl(e0[k], a, 64);        // 0 for padded atoms
                float w1v = __shfl(e1[k], a, 64);
                float w2v = __shfl(e2[k], a, 64);
                float4 f = make_float4(0.f, 0.f, 0.f, 0.f);
                if (a < cnt)
                    f = *(const float4*)(base + (size_t)a * DD + c * 4);
                A0.x += f.x * w0;  A0.y += f.y * w0;  A0.z += f.z * w0;  A0.w += f.w * w0;
                A1.x += f.x * w1v; A1.y += f.y * w1v; A1.z += f.z * w1v; A1.w += f.w * w1v;
                A2.x += f.x * w2v; A2.y += f.y * w2v; A2.z += f.z * w2v; A2.w += f.w * w2v;
            }
        }
    }
    A0 = xor_reduce_16_32(A0);
    A1 = xor_reduce_16_32(A1);
    A2 = xor_reduce_16_32(A2);
    A0.x *= rd0; A0.y *= rd0; A0.z *= rd0; A0.w *= rd0;
    A1.x *= rd1; A1.y *= rd1; A1.z *= rd1; A1.w *= rd1;
    A2.x *= rd2; A2.y *= rd2; A2.z *= rd2; A2.w *= rd2;

    // out[g, d, h] head-fastest: lane c owns 12 consecutive floats at 48c;
    // lanes sub=0..2 each store one float4 -> 768B contiguous per segment.
    float4 w;
    if (sub == 0)      w = make_float4(A0.x, A1.x, A2.x, A0.y);
    else if (sub == 1) w = make_float4(A1.y, A2.y, A0.z, A1.z);
    else               w = make_float4(A2.z, A0.w, A1.w, A2.w);
    if (sub < 3)
        *(float4*)(outg + c * 12 + sub * 4) = w;
}

// ---------------------------------------------------------------------------
// Fused fallback (only if workspace can't hold scores): previous-best kernel.
// ---------------------------------------------------------------------------
static __device__ __attribute__((noinline)) void big_segment_path_fused(
    const float* __restrict__ feas, const float* __restrict__ w1,
    const float* __restrict__ b1, const float* __restrict__ w2,
    const float* __restrict__ b2, float* __restrict__ sc,
    int lo, int hi, int lane, float* __restrict__ outg) {
    float m0 = -INFINITY, m1 = -INFINITY, m2 = -INFINITY;
    for (int base = lo; base < hi; base += 64) {
        int a = base + lane;
        if (a < hi) {
            float s0, s1, s2;
            mlp_scores(feas + (size_t)a * DD, w1, b1, w2, b2, s0, s1, s2);
            m0 = fmaxf(m0, s0); m1 = fmaxf(m1, s1); m2 = fmaxf(m2, s2);
        }
    }
    m0 = wave_max(m0); m1 = wave_max(m1); m2 = wave_max(m2);
    float d0 = 0.f, d1 = 0.f, d2 = 0.f;
    for (int base = lo; base < hi; base += 64) {
        int a = base + lane;
        if (a < hi) {
            float s0, s1, s2;
            mlp_scores(feas + (size_t)a * DD, w1, b1, w2, b2, s0, s1, s2);
            d0 += __expf(s0 - m0); d1 += __expf(s1 - m1); d2 += __expf(s2 - m2);
        }
    }
    d0 = wave_sum(d0); d1 = wave_sum(d1); d2 = wave_sum(d2);
    float rd0 = __builtin_amdgcn_rcpf(d0);
    float rd1 = __builtin_amdgcn_rcpf(d1);
    float rd2 = __builtin_amdgcn_rcpf(d2);
    float a0 = 0.f, a1 = 0.f, a2 = 0.f;
    for (int base = lo; base < hi; base += 64) {
        int a = base + lane;
        int cnt = min(64, hi - base);
        __syncthreads();
        if (a < hi) {
            float s0, s1, s2;
            mlp_scores(feas + (size_t)a * DD, w1, b1, w2, b2, s0, s1, s2);
            sc[lane * 3 + 0] = __expf(s0 - m0);
            sc[lane * 3 + 1] = __expf(s1 - m1);
            sc[lane * 3 + 2] = __expf(s2 - m2);
        }
        __syncthreads();
        for (int i = 0; i < cnt; ++i) {
            float f = feas[(size_t)(base + i) * DD + lane];
            a0 += f * sc[i * 3 + 0];
            a1 += f * sc[i * 3 + 1];
            a2 += f * sc[i * 3 + 2];
        }
    }
    outg[lane * 3 + 0] = a0 * rd0;
    outg[lane * 3 + 1] = a1 * rd1;
    outg[lane * 3 + 2] = a2 * rd2;
}

__global__ void __launch_bounds__(64) seg_attn_pool_fused_k(
    const float* __restrict__ feas, const float* __restrict__ w1,
    const float* __restrict__ b1, const float* __restrict__ w2,
    const float* __restrict__ b2, const int* __restrict__ seg_start,
    float* __restrict__ out) {
    __shared__ float sc[SMAX_LDS * 3];
    const int g = blockIdx.x;
    const int lane = threadIdx.x;
    const int lo = seg_start[g];
    const int hi = seg_start[g + 1];
    const int seg = hi - lo;
    float* outg = out + (size_t)g * (DD * NH);

    if (seg <= 0) {
        outg[lane] = 0.f; outg[lane + 64] = 0.f; outg[lane + 128] = 0.f;
        return;
    }
    if (seg > SMAX_LDS) {
        big_segment_path_fused(feas, w1, b1, w2, b2, sc, lo, hi, lane, outg);
        return;
    }
    for (int base = 0; base < seg; base += 64) {
        int i = base + lane;
        if (i < seg) {
            float s0, s1, s2;
            mlp_scores(feas + (size_t)(lo + i) * DD, w1, b1, w2, b2, s0, s1, s2);
            sc[i * 3 + 0] = s0; sc[i * 3 + 1] = s1; sc[i * 3 + 2] = s2;
        }
    }
    __syncthreads();
    float m0 = -INFINITY, m1 = -INFINITY, m2 = -INFINITY;
    for (int i = lane; i < seg; i += 64) {
        m0 = fmaxf(m0, sc[i * 3 + 0]);
        m1 = fmaxf(m1, sc[i * 3 + 1]);
        m2 = fmaxf(m2, sc[i * 3 + 2]);
    }
    m0 = wave_max(m0); m1 = wave_max(m1); m2 = wave_max(m2);
    float d0 = 0.f, d1 = 0.f, d2 = 0.f;
    for (int i = lane; i < seg; i += 64) {
        float e0 = __expf(sc[i * 3 + 0] - m0);
        float e1 = __expf(sc[i * 3 + 1] - m1);
        float e2 = __expf(sc[i * 3 + 2] - m2);
        sc[i * 3 + 0] = e0; sc[i * 3 + 1] = e1; sc[i * 3 + 2] = e2;
        d0 += e0; d1 += e1; d2 += e2;
    }
    __syncthreads();
    d0 = wave_sum(d0); d1 = wave_sum(d1); d2 = wave_sum(d2);
    const float rd0 = __builtin_amdgcn_rcpf(d0);
    const float rd1 = __builtin_amdgcn_rcpf(d1);
    const float rd2 = __builtin_amdgcn_rcpf(d2);
    float a0 = 0.f, a1 = 0.f, a2 = 0.f;
    const float* fbase = feas + (size_t)lo * DD + lane;
    for (int i = 0; i < seg; ++i) {
        float f = fbase[(size_t)i * DD];
        a0 += f * sc[i * 3 + 0];
        a1 += f * sc[i * 3 + 1];
        a2 += f * sc[i * 3 + 2];
    }
    outg[lane * 3 + 0] = a0 * rd0;
    outg[lane * 3 + 1] = a1 * rd1;
    outg[lane * 3 + 2] = a2 * rd2;
}

extern "C" void kernel_launch(void* const* d_in, const int* in_sizes, int n_in,
                              void* d_out, int out_size, void* d_ws, size_t ws_size,
                              hipStream_t stream) {
    const float* feas  = (const float*)d_in[0];
    const float* w1    = (const float*)d_in[1];
    const float* b1    = (const float*)d_in[2];
    const float* w2    = (const float*)d_in[3];
    const float* b2    = (const float*)d_in[4];
    const int*   owner = (const int*)d_in[5];
    const int N = in_sizes[5];
    const int G = out_size / (DD * NH);

    int* seg_start = (int*)d_ws;                         // (G+1) ints
    size_t off = (((size_t)(G + 1) * sizeof(int)) + 255) & ~(size_t)255;
    float4* scores = (float4*)((char*)d_ws + off);       // [N] float4 (padded)
    size_t need = off + (size_t)N * sizeof(float4);
    float* out = (float*)d_out;

    seg_offsets_k<<<(N + 255) / 256, 256, 0, stream>>>(owner, N, G, seg_start);
    if (ws_size >= need) {
        scores_k<<<(N + SROWS - 1) / SROWS, 256, 0, stream>>>(feas, w1, b1, w2, b2, N, scores);
        pool_k<<<(G + 3) / 4, 256, 0, stream>>>(feas, scores, seg_start, G, out);
    } else {
        seg_attn_pool_fused_k<<<G, 64, 0, stream>>>(feas, w1, b1, w2, b2, seg_start, out);
    }
}

// Round 5
// 780.396 us; speedup vs baseline: 1.1259x; 1.1259x over previous
//
#include <hip/hip_runtime.h>
#include <math.h>

#define DD 64
#define HIDN 32
#define NH 3
#define KMAX 4                      // pool fast path: up to 256 atoms/segment
#define SMAX_FAST (KMAX * 64)
#define SMAX_LDS 512                // fused-fallback LDS capacity

typedef __attribute__((ext_vector_type(8))) short bf16x8;
typedef __attribute__((ext_vector_type(4))) float f32x4;

// ---------------------------------------------------------------------------
// bf16 split helpers (RNE)
// ---------------------------------------------------------------------------
static __device__ __forceinline__ short f2bf(float f) {
    unsigned u = __float_as_uint(f);
    unsigned r = u + 0x7fffu + ((u >> 16) & 1u);
    return (short)(r >> 16);
}
static __device__ __forceinline__ float bf2f(short h) {
    return __uint_as_float(((unsigned)(unsigned short)h) << 16);
}

// ---------------------------------------------------------------------------
// Kernel 1: segment offsets (lower_bound on sorted owner, gap-filled).
// ---------------------------------------------------------------------------
__global__ void seg_offsets_k(const int* __restrict__ owner, int N, int G,
                              int* __restrict__ seg_start) {
    int i = blockIdx.x * blockDim.x + threadIdx.x;
    if (i >= N) return;
    int cur  = owner[i];
    int prev = (i == 0) ? -1 : owner[i - 1];
    for (int g = prev + 1; g <= cur; ++g) seg_start[g] = i;
    if (i == N - 1) {
        for (int g = cur + 1; g <= G; ++g) seg_start[g] = N;
    }
}

// ---------------------------------------------------------------------------
// Generic per-atom MLP (fallback paths). fp32 throughout.
// ---------------------------------------------------------------------------
static __device__ __forceinline__ void mlp_scores(
    const float* __restrict__ fr, const float* __restrict__ w1,
    const float* __restrict__ b1, const float* __restrict__ w2,
    const float* __restrict__ b2, float& s0, float& s1, float& s2) {
    float hid[HIDN];
#pragma unroll
    for (int j = 0; j < HIDN; ++j) hid[j] = b1[j];
    const float4* fr4 = (const float4*)fr;
    for (int q = 0; q < DD / 4; ++q) {
        float4 f = fr4[q];
        const float* w1r = w1 + (q * 4) * HIDN;
#pragma unroll
        for (int j = 0; j < HIDN; ++j) {
            hid[j] += f.x * w1r[j];
            hid[j] += f.y * w1r[HIDN + j];
            hid[j] += f.z * w1r[2 * HIDN + j];
            hid[j] += f.w * w1r[3 * HIDN + j];
        }
    }
    s0 = b2[0]; s1 = b2[1]; s2 = b2[2];
#pragma unroll
    for (int j = 0; j < HIDN; ++j) {
        float v = hid[j];
        v = v * __builtin_amdgcn_rcpf(1.0f + __expf(-v));   // silu
        s0 += v * w2[j * NH + 0];
        s1 += v * w2[j * NH + 1];
        s2 += v * w2[j * NH + 2];
    }
}

static __device__ __forceinline__ float wave_max(float v) {
#pragma unroll
    for (int m = 32; m >= 1; m >>= 1) v = fmaxf(v, __shfl_xor(v, m, 64));
    return v;
}
static __device__ __forceinline__ float wave_sum(float v) {
#pragma unroll
    for (int m = 32; m >= 1; m >>= 1) v += __shfl_xor(v, m, 64);
    return v;
}

// ---------------------------------------------------------------------------
// MFMA layout self-check: one wave verifies the assumed 16x16x32 bf16
// fragment mapping (A[m=l&15][k=(l>>4)*8+j], B[k=(l>>4)*8+j][n=l&15],
// D[row=(l>>4)*4+reg][col=l&15]) against an exact integer reference.
// flag = 0 ok, 1 mismatch (fixup kernel then recomputes scores in VALU).
// ---------------------------------------------------------------------------
__global__ void mfma_check_k(int* __restrict__ flag) {
    const int lane = threadIdx.x;
    const int m = lane & 15, kg = lane >> 4;
    bf16x8 a, b;
#pragma unroll
    for (int j = 0; j < 8; ++j) {
        int k = kg * 8 + j;
        a[j] = f2bf((float)((m * 3 + k) % 7 - 3));
        b[j] = f2bf((float)((k * 5 + m * 2) % 9 - 4));
    }
    f32x4 c = {0.f, 0.f, 0.f, 0.f};
    c = __builtin_amdgcn_mfma_f32_16x16x32_bf16(a, b, c, 0, 0, 0);
    bool ok = true;
#pragma unroll
    for (int reg = 0; reg < 4; ++reg) {
        int row = kg * 4 + reg, col = m;
        float ref = 0.f;
        for (int k = 0; k < 32; ++k)
            ref += (float)((row * 3 + k) % 7 - 3) * (float)((k * 5 + col * 2) % 9 - 4);
        ok = ok && (fabsf(c[reg] - ref) < 0.5f);
    }
    unsigned long long vote = __ballot(ok);
    if (lane == 0) *flag = (vote == 0xFFFFFFFFFFFFFFFFull) ? 0 : 1;
}

// ---------------------------------------------------------------------------
// Kernel 2: scores via MFMA. Each wave handles 64 atoms independently
// (no barriers). hid[64x32] = split-bf16 MFMA (3 terms: hi*hi+hi*lo+lo*hi,
// error ~2^-17 rel). silu'd hid goes to a per-wave LDS strip; stage 2
// (32->3) is a 96-FMA per-thread dot. Memory: one coalesced pass of feas.
// ---------------------------------------------------------------------------
__global__ void __launch_bounds__(256, 2) scores_mfma_k(
    const float* __restrict__ feas, const float* __restrict__ w1,
    const float* __restrict__ b1, const float* __restrict__ w2,
    const float* __restrict__ b2, int N, float4* __restrict__ scores) {
    __shared__ float hidLds[4 * 64 * 33];       // 33792 B, per-wave strips
    const int wid  = threadIdx.x >> 6;
    const int lane = threadIdx.x & 63;
    const int atom0 = blockIdx.x * 256 + wid * 64;
    if (atom0 >= N) return;                      // no barriers -> safe

    const int bn = lane & 15;                    // col within tile
    const int kg = lane >> 4;                    // k-group / row-group

    // ---- B fragments from w1 [64][32] (hot in cache, gathered once/wave)
    bf16x8 Bhi[2][2], Blo[2][2];                 // [nt][ks]
#pragma unroll
    for (int nt = 0; nt < 2; ++nt)
#pragma unroll
        for (int ks = 0; ks < 2; ++ks)
#pragma unroll
            for (int j = 0; j < 8; ++j) {
                int k = ks * 32 + kg * 8 + j;
                float w = w1[k * HIDN + nt * 16 + bn];
                short h = f2bf(w);
                Bhi[nt][ks][j] = h;
                Blo[nt][ks][j] = f2bf(w - bf2f(h));
            }

    // ---- acc init = b1 broadcast (C/D col = lane&15)
    float b1v0 = b1[bn], b1v1 = b1[16 + bn];
    f32x4 acc[4][2];
#pragma unroll
    for (int mt = 0; mt < 4; ++mt) {
        acc[mt][0] = (f32x4){b1v0, b1v0, b1v0, b1v0};
        acc[mt][1] = (f32x4){b1v1, b1v1, b1v1, b1v1};
    }

    // ---- A tiles: 16 rows each; lane reads its 8-dim chunks (coalesced:
    // one instruction = 16 rows x 16B, consecutive instrs fill the lines)
#pragma unroll
    for (int mt = 0; mt < 4; ++mt) {
        int r = atom0 + mt * 16 + bn;
        if (r >= N) r = N - 1;                   // tail clamp (discarded)
        const float4* rp = (const float4*)(feas + (size_t)r * DD);
        float4 x0 = rp[kg * 2 + 0];              // ks=0 dims kg*8..+4
        float4 x1 = rp[kg * 2 + 1];              // ks=0 dims kg*8+4..+8
        float4 x2 = rp[8 + kg * 2 + 0];          // ks=1
        float4 x3 = rp[8 + kg * 2 + 1];
        float xf0[8] = {x0.x, x0.y, x0.z, x0.w, x1.x, x1.y, x1.z, x1.w};
        float xf1[8] = {x2.x, x2.y, x2.z, x2.w, x3.x, x3.y, x3.z, x3.w};
        bf16x8 Ahi0, Alo0, Ahi1, Alo1;
#pragma unroll
        for (int j = 0; j < 8; ++j) {
            short h0 = f2bf(xf0[j]); Ahi0[j] = h0; Alo0[j] = f2bf(xf0[j] - bf2f(h0));
            short h1 = f2bf(xf1[j]); Ahi1[j] = h1; Alo1[j] = f2bf(xf1[j] - bf2f(h1));
        }
#pragma unroll
        for (int nt = 0; nt < 2; ++nt) {
            acc[mt][nt] = __builtin_amdgcn_mfma_f32_16x16x32_bf16(Ahi0, Bhi[nt][0], acc[mt][nt], 0, 0, 0);
            acc[mt][nt] = __builtin_amdgcn_mfma_f32_16x16x32_bf16(Ahi1, Bhi[nt][1], acc[mt][nt], 0, 0, 0);
            acc[mt][nt] = __builtin_amdgcn_mfma_f32_16x16x32_bf16(Ahi0, Blo[nt][0], acc[mt][nt], 0, 0, 0);
            acc[mt][nt] = __builtin_amdgcn_mfma_f32_16x16x32_bf16(Ahi1, Blo[nt][1], acc[mt][nt], 0, 0, 0);
            acc[mt][nt] = __builtin_amdgcn_mfma_f32_16x16x32_bf16(Alo0, Bhi[nt][0], acc[mt][nt], 0, 0, 0);
            acc[mt][nt] = __builtin_amdgcn_mfma_f32_16x16x32_bf16(Alo1, Bhi[nt][1], acc[mt][nt], 0, 0, 0);
        }
    }

    // ---- silu -> per-wave LDS (pitch 33: odd -> conflict-light)
    float* hw = &hidLds[wid * 64 * 33];
#pragma unroll
    for (int mt = 0; mt < 4; ++mt)
#pragma unroll
        for (int nt = 0; nt < 2; ++nt)
#pragma unroll
            for (int reg = 0; reg < 4; ++reg) {
                float v = acc[mt][nt][reg];
                v = v * __builtin_amdgcn_rcpf(1.0f + __expf(-v));
                hw[(mt * 16 + kg * 4 + reg) * 33 + nt * 16 + bn] = v;
            }
    // same-wave LDS RAW: drain ds queue, pin ordering (guide rule 18)
    __asm__ volatile("s_waitcnt lgkmcnt(0)" ::: "memory");
    __builtin_amdgcn_sched_barrier(0);

    // ---- stage 2: thread=atom, 32->3 dot (w2/b2 lane-uniform scalar loads)
    const float* hr = hw + lane * 33;
    float s0 = b2[0], s1 = b2[1], s2 = b2[2];
#pragma unroll
    for (int j = 0; j < HIDN; ++j) {
        float v = hr[j];
        s0 += v * w2[j * NH + 0];
        s1 += v * w2[j * NH + 1];
        s2 += v * w2[j * NH + 2];
    }
    if (atom0 + lane < N)
        scores[atom0 + lane] = make_float4(s0, s1, s2, 0.0f);
}

// ---------------------------------------------------------------------------
// Fixup: if the MFMA layout check failed, recompute all scores in VALU
// (round-3 burst-load form). Early-exits in ~µs when flag == 0.
// ---------------------------------------------------------------------------
__global__ void __launch_bounds__(256) scores_fixup_k(
    const float* __restrict__ feas, const float* __restrict__ w1,
    const float* __restrict__ b1, const float* __restrict__ w2,
    const float* __restrict__ b2, int N, float4* __restrict__ scores,
    const int* __restrict__ flag) {
    if (*flag == 0) return;
    int i = blockIdx.x * 256 + threadIdx.x;
    if (i >= N) return;
    float s0, s1, s2;
    mlp_scores(feas + (size_t)i * DD, w1, b1, w2, b2, s0, s1, s2);
    scores[i] = make_float4(s0, s1, s2, 0.0f);
}

// ---------------------------------------------------------------------------
// Big-segment pooling fallback (seg > 256). Rare (mean seg = 40).
// ---------------------------------------------------------------------------
static __device__ __attribute__((noinline)) void big_pool(
    const float* __restrict__ feas, const float4* __restrict__ scores,
    int lo, int hi, int lane, float* __restrict__ outg) {
    float m0 = -INFINITY, m1 = -INFINITY, m2 = -INFINITY;
    for (int i = lo + lane; i < hi; i += 64) {
        float4 s = scores[i];
        m0 = fmaxf(m0, s.x); m1 = fmaxf(m1, s.y); m2 = fmaxf(m2, s.z);
    }
    m0 = wave_max(m0); m1 = wave_max(m1); m2 = wave_max(m2);
    float d0 = 0.f, d1 = 0.f, d2 = 0.f;
    for (int i = lo + lane; i < hi; i += 64) {
        float4 s = scores[i];
        d0 += __expf(s.x - m0); d1 += __expf(s.y - m1); d2 += __expf(s.z - m2);
    }
    d0 = wave_sum(d0); d1 = wave_sum(d1); d2 = wave_sum(d2);
    float a0 = 0.f, a1 = 0.f, a2 = 0.f;
    for (int base = lo; base < hi; base += 64) {
        int i = base + lane;
        float e0v = 0.f, e1v = 0.f, e2v = 0.f;
        if (i < hi) {
            float4 s = scores[i];
            e0v = __expf(s.x - m0); e1v = __expf(s.y - m1); e2v = __expf(s.z - m2);
        }
        int cnt = min(64, hi - base);
        for (int j = 0; j < cnt; ++j) {
            float f = feas[(size_t)(base + j) * DD + lane];
            a0 += f * __shfl(e0v, j, 64);
            a1 += f * __shfl(e1v, j, 64);
            a2 += f * __shfl(e2v, j, 64);
        }
    }
    outg[lane * 3 + 0] = a0 * __builtin_amdgcn_rcpf(d0);
    outg[lane * 3 + 1] = a1 * __builtin_amdgcn_rcpf(d1);
    outg[lane * 3 + 2] = a2 * __builtin_amdgcn_rcpf(d2);
}

// ---------------------------------------------------------------------------
// Kernel 3: segment softmax + pooling, v3. 4 waves/block, one segment per
// wave, NO barriers. Softmax in registers (as v2). exp-weights written once
// to a per-wave LDS strip; phase 3 = v1's proven coalesced lane=dim scalar
// loads (64 lanes x 4B = 256B/instr) with 4 independent rows in flight and
// FREE uniform-address LDS broadcasts for weights (no ds_bpermute chains —
// v2's per-lane shfl was the regression).
// ---------------------------------------------------------------------------
__global__ void __launch_bounds__(256, 4) pool_k(
    const float* __restrict__ feas, const float4* __restrict__ scores,
    const int* __restrict__ seg_start, int G, float* __restrict__ out) {
    __shared__ float swAll[4 * SMAX_FAST * 3];   // 12 KB, per-wave strips
    const int wid  = threadIdx.x >> 6;
    const int lane = threadIdx.x & 63;
    const int gi = blockIdx.x * 4 + wid;
    if (gi >= G) return;
    const int g = G - 1 - gi;                    // reverse order: L3 reuse
    const int lo = seg_start[g];
    const int hi = seg_start[g + 1];
    const int seg = hi - lo;
    float* outg = out + (size_t)g * (DD * NH);

    if (seg <= 0) {
        outg[lane] = 0.f; outg[lane + 64] = 0.f; outg[lane + 128] = 0.f;
        return;
    }
    if (seg > SMAX_FAST) {
        big_pool(feas, scores, lo, hi, lane, outg);
        return;
    }

    // ---- Phase 1: scores -> regs, wave max
    float e0[KMAX], e1[KMAX], e2[KMAX];
    float m0 = -INFINITY, m1 = -INFINITY, m2 = -INFINITY;
#pragma unroll
    for (int k = 0; k < KMAX; ++k) {
        int i = k * 64 + lane;
        if (i < seg) {
            float4 s = scores[lo + i];
            e0[k] = s.x; e1[k] = s.y; e2[k] = s.z;
        } else {
            e0[k] = -INFINITY; e1[k] = -INFINITY; e2[k] = -INFINITY;
        }
        m0 = fmaxf(m0, e0[k]); m1 = fmaxf(m1, e1[k]); m2 = fmaxf(m2, e2[k]);
    }
    m0 = wave_max(m0); m1 = wave_max(m1); m2 = wave_max(m2);

    // ---- Phase 2: exp + denominators (padded lanes -> 0)
    float d0 = 0.f, d1 = 0.f, d2 = 0.f;
#pragma unroll
    for (int k = 0; k < KMAX; ++k) {
        if (k * 64 < seg) {
            e0[k] = __expf(e0[k] - m0); d0 += e0[k];
            e1[k] = __expf(e1[k] - m1); d1 += e1[k];
            e2[k] = __expf(e2[k] - m2); d2 += e2[k];
        } else {
            e0[k] = 0.f; e1[k] = 0.f; e2[k] = 0.f;
        }
    }
    d0 = wave_sum(d0); d1 = wave_sum(d1); d2 = wave_sum(d2);
    const float rd0 = __builtin_amdgcn_rcpf(d0);
    const float rd1 = __builtin_amdgcn_rcpf(d1);
    const float rd2 = __builtin_amdgcn_rcpf(d2);

    // ---- weights -> per-wave LDS (stride 3: coprime banks, 2-way = free)
    float* sw = &swAll[wid * SMAX_FAST * 3];
#pragma unroll
    for (int k = 0; k < KMAX; ++k) {
        int i = k * 64 + lane;
        sw[i * 3 + 0] = e0[k]; sw[i * 3 + 1] = e1[k]; sw[i * 3 + 2] = e2[k];
    }
    __asm__ volatile("s_waitcnt lgkmcnt(0)" ::: "memory");   // same-wave RAW
    __builtin_amdgcn_sched_barrier(0);

    // ---- Phase 3: lane = dim; 4 independent coalesced row loads per iter,
    // weights via uniform-address LDS broadcast (free).
    float a0 = 0.f, a1 = 0.f, a2 = 0.f;
    const float* fb = feas + (size_t)lo * DD + lane;
    int i = 0;
    for (; i + 4 <= seg; i += 4) {
        float f0 = fb[(size_t)(i + 0) * DD];
        float f1 = fb[(size_t)(i + 1) * DD];
        float f2 = fb[(size_t)(i + 2) * DD];
        float f3 = fb[(size_t)(i + 3) * DD];
        a0 += f0 * sw[(i + 0) * 3 + 0]; a1 += f0 * sw[(i + 0) * 3 + 1]; a2 += f0 * sw[(i + 0) * 3 + 2];
        a0 += f1 * sw[(i + 1) * 3 + 0]; a1 += f1 * sw[(i + 1) * 3 + 1]; a2 += f1 * sw[(i + 1) * 3 + 2];
        a0 += f2 * sw[(i + 2) * 3 + 0]; a1 += f2 * sw[(i + 2) * 3 + 1]; a2 += f2 * sw[(i + 2) * 3 + 2];
        a0 += f3 * sw[(i + 3) * 3 + 0]; a1 += f3 * sw[(i + 3) * 3 + 1]; a2 += f3 * sw[(i + 3) * 3 + 2];
    }
    for (; i < seg; ++i) {
        float f = fb[(size_t)i * DD];
        a0 += f * sw[i * 3 + 0]; a1 += f * sw[i * 3 + 1]; a2 += f * sw[i * 3 + 2];
    }
    // out[g, d, h] head-fastest: 12B/lane, 768B contiguous per segment
    outg[lane * 3 + 0] = a0 * rd0;
    outg[lane * 3 + 1] = a1 * rd1;
    outg[lane * 3 + 2] = a2 * rd2;
}

// ---------------------------------------------------------------------------
// Fused fallback (only if workspace can't hold scores).
// ---------------------------------------------------------------------------
static __device__ __attribute__((noinline)) void big_segment_path_fused(
    const float* __restrict__ feas, const float* __restrict__ w1,
    const float* __restrict__ b1, const float* __restrict__ w2,
    const float* __restrict__ b2, float* __restrict__ sc,
    int lo, int hi, int lane, float* __restrict__ outg) {
    float m0 = -INFINITY, m1 = -INFINITY, m2 = -INFINITY;
    for (int base = lo; base < hi; base += 64) {
        int a = base + lane;
        if (a < hi) {
            float s0, s1, s2;
            mlp_scores(feas + (size_t)a * DD, w1, b1, w2, b2, s0, s1, s2);
            m0 = fmaxf(m0, s0); m1 = fmaxf(m1, s1); m2 = fmaxf(m2, s2);
        }
    }
    m0 = wave_max(m0); m1 = wave_max(m1); m2 = wave_max(m2);
    float d0 = 0.f, d1 = 0.f, d2 = 0.f;
    for (int base = lo; base < hi; base += 64) {
        int a = base + lane;
        if (a < hi) {
            float s0, s1, s2;
            mlp_scores(feas + (size_t)a * DD, w1, b1, w2, b2, s0, s1, s2);
            d0 += __expf(s0 - m0); d1 += __expf(s1 - m1); d2 += __expf(s2 - m2);
        }
    }
    d0 = wave_sum(d0); d1 = wave_sum(d1); d2 = wave_sum(d2);
    float rd0 = __builtin_amdgcn_rcpf(d0);
    float rd1 = __builtin_amdgcn_rcpf(d1);
    float rd2 = __builtin_amdgcn_rcpf(d2);
    float a0 = 0.f, a1 = 0.f, a2 = 0.f;
    for (int base = lo; base < hi; base += 64) {
        int a = base + lane;
        int cnt = min(64, hi - base);
        __syncthreads();
        if (a < hi) {
            float s0, s1, s2;
            mlp_scores(feas + (size_t)a * DD, w1, b1, w2, b2, s0, s1, s2);
            sc[lane * 3 + 0] = __expf(s0 - m0);
            sc[lane * 3 + 1] = __expf(s1 - m1);
            sc[lane * 3 + 2] = __expf(s2 - m2);
        }
        __syncthreads();
        for (int i = 0; i < cnt; ++i) {
            float f = feas[(size_t)(base + i) * DD + lane];
            a0 += f * sc[i * 3 + 0];
            a1 += f * sc[i * 3 + 1];
            a2 += f * sc[i * 3 + 2];
        }
    }
    outg[lane * 3 + 0] = a0 * rd0;
    outg[lane * 3 + 1] = a1 * rd1;
    outg[lane * 3 + 2] = a2 * rd2;
}

__global__ void __launch_bounds__(64) seg_attn_pool_fused_k(
    const float* __restrict__ feas, const float* __restrict__ w1,
    const float* __restrict__ b1, const float* __restrict__ w2,
    const float* __restrict__ b2, const int* __restrict__ seg_start,
    float* __restrict__ out) {
    __shared__ float sc[SMAX_LDS * 3];
    const int g = blockIdx.x;
    const int lane = threadIdx.x;
    const int lo = seg_start[g];
    const int hi = seg_start[g + 1];
    const int seg = hi - lo;
    float* outg = out + (size_t)g * (DD * NH);
    if (seg <= 0) {
        outg[lane] = 0.f; outg[lane + 64] = 0.f; outg[lane + 128] = 0.f;
        return;
    }
    if (seg > SMAX_LDS) {
        big_segment_path_fused(feas, w1, b1, w2, b2, sc, lo, hi, lane, outg);
        return;
    }
    for (int base = 0; base < seg; base += 64) {
        int i = base + lane;
        if (i < seg) {
            float s0, s1, s2;
            mlp_scores(feas + (size_t)(lo + i) * DD, w1, b1, w2, b2, s0, s1, s2);
            sc[i * 3 + 0] = s0; sc[i * 3 + 1] = s1; sc[i * 3 + 2] = s2;
        }
    }
    __syncthreads();
    float m0 = -INFINITY, m1 = -INFINITY, m2 = -INFINITY;
    for (int i = lane; i < seg; i += 64) {
        m0 = fmaxf(m0, sc[i * 3 + 0]);
        m1 = fmaxf(m1, sc[i * 3 + 1]);
        m2 = fmaxf(m2, sc[i * 3 + 2]);
    }
    m0 = wave_max(m0); m1 = wave_max(m1); m2 = wave_max(m2);
    float d0 = 0.f, d1 = 0.f, d2 = 0.f;
    for (int i = lane; i < seg; i += 64) {
        float e0 = __expf(sc[i * 3 + 0] - m0);
        float e1 = __expf(sc[i * 3 + 1] - m1);
        float e2 = __expf(sc[i * 3 + 2] - m2);
        sc[i * 3 + 0] = e0; sc[i * 3 + 1] = e1; sc[i * 3 + 2] = e2;
        d0 += e0; d1 += e1; d2 += e2;
    }
    __syncthreads();
    d0 = wave_sum(d0); d1 = wave_sum(d1); d2 = wave_sum(d2);
    const float rd0 = __builtin_amdgcn_rcpf(d0);
    const float rd1 = __builtin_amdgcn_rcpf(d1);
    const float rd2 = __builtin_amdgcn_rcpf(d2);
    float a0 = 0.f, a1 = 0.f, a2 = 0.f;
    const float* fbase = feas + (size_t)lo * DD + lane;
    for (int i = 0; i < seg; ++i) {
        float f = fbase[(size_t)i * DD];
        a0 += f * sc[i * 3 + 0];
        a1 += f * sc[i * 3 + 1];
        a2 += f * sc[i * 3 + 2];
    }
    outg[lane * 3 + 0] = a0 * rd0;
    outg[lane * 3 + 1] = a1 * rd1;
    outg[lane * 3 + 2] = a2 * rd2;
}

extern "C" void kernel_launch(void* const* d_in, const int* in_sizes, int n_in,
                              void* d_out, int out_size, void* d_ws, size_t ws_size,
                              hipStream_t stream) {
    const float* feas  = (const float*)d_in[0];
    const float* w1    = (const float*)d_in[1];
    const float* b1    = (const float*)d_in[2];
    const float* w2    = (const float*)d_in[3];
    const float* b2    = (const float*)d_in[4];
    const int*   owner = (const int*)d_in[5];
    const int N = in_sizes[5];
    const int G = out_size / (DD * NH);

    int* seg_start = (int*)d_ws;                         // (G+1) ints
    size_t off = (((size_t)(G + 1) * sizeof(int)) + 255) & ~(size_t)255;
    float4* scores = (float4*)((char*)d_ws + off);       // [N] float4
    size_t foff = off + (size_t)N * sizeof(float4);
    foff = (foff + 255) & ~(size_t)255;
    int* flag = (int*)((char*)d_ws + foff);
    size_t need = foff + 256;
    float* out = (float*)d_out;

    seg_offsets_k<<<(N + 255) / 256, 256, 0, stream>>>(owner, N, G, seg_start);
    if (ws_size >= need) {
        mfma_check_k<<<1, 64, 0, stream>>>(flag);
        scores_mfma_k<<<(N + 255) / 256, 256, 0, stream>>>(feas, w1, b1, w2, b2, N, scores);
        scores_fixup_k<<<(N + 255) / 256, 256, 0, stream>>>(feas, w1, b1, w2, b2, N, scores, flag);
        pool_k<<<(G + 3) / 4, 256, 0, stream>>>(feas, scores, seg_start, G, out);
    } else {
        seg_attn_pool_fused_k<<<G, 64, 0, stream>>>(feas, w1, b1, w2, b2, seg_start, out);
    }
}